// Round 2
// baseline (44360.187 us; speedup 1.0000x reference)
//
#include <hip/hip_runtime.h>
#include <cstdint>
#include <cstddef>

using u16 = unsigned short;
using u32 = unsigned int;

typedef __attribute__((ext_vector_type(8))) __bf16 bf16x8;
typedef __attribute__((ext_vector_type(4))) float f32x4;

__device__ __forceinline__ float bf2f(u16 u){
  union { u32 i; float f; } v; v.i = ((u32)u) << 16; return v.f;
}
__device__ __forceinline__ u16 f2bf(float f){
  union { float f; u32 i; } v; v.f = f;
  return (u16)((v.i + 0x7FFFu + ((v.i >> 16) & 1u)) >> 16);
}
__device__ __forceinline__ float sigm(float x){ return 1.0f / (1.0f + __expf(-x)); }
__device__ __forceinline__ f32x4 mfma16(bf16x8 a, bf16x8 b, f32x4 c){
  return __builtin_amdgcn_mfma_f32_16x16x32_bf16(a, b, c, 0, 0, 0);
}
// dtype-agnostic scalar load (f32 buffer or bf16 buffer)
__device__ __forceinline__ float ldin(const void* p, size_t i, bool f){
  return f ? ((const float*)p)[i] : bf2f(((const u16*)p)[i]);
}

// device-scope barrier: monotonic counter, target = gen * nwg
__device__ __forceinline__ void gbar(u32* bar, u32 target){
  __syncthreads();
  if (threadIdx.x == 0){
    __hip_atomic_fetch_add(bar, 1u, __ATOMIC_ACQ_REL, __HIP_MEMORY_SCOPE_AGENT);
    while (__hip_atomic_load(bar, __ATOMIC_RELAXED, __HIP_MEMORY_SCOPE_AGENT) < target)
      __builtin_amdgcn_s_sleep(1);
    (void)__hip_atomic_load(bar, __ATOMIC_ACQUIRE, __HIP_MEMORY_SCOPE_AGENT);
  }
  __syncthreads();
}

// ---------------- dtype detection ----------------
// If the buffer holds f32, the LOW u16 of each dword is ~uniform mantissa bits:
// ~25% have bf16-exponent >= 0xC0 (|x| >= 2^65). Real bf16 data (|x|<1) never does.
__global__ __launch_bounds__(256) void k_detect(const u32* __restrict__ embw, u32* __restrict__ dflag){
  int tid = threadIdx.x;
  u32 cnt = 0;
  for (int t = 0; t < 32; ++t){
    u32 w = embw[t*256 + tid];
    u32 e = (w >> 7) & 0xFFu;
    cnt += (e >= 0xC0u) ? 1u : 0u;
  }
  atomicAdd(dflag, cnt);
}

// ---------------- pack (weights -> bf16/f32 in ws) ----------------

__global__ __launch_bounds__(256) void k_pack(
  const void* eWihF, const void* eWihB, const void* ebF, const void* ebB,
  const void* dWih, const void* dWhh, const void* db, const void* Wtag,
  const void* eWhhF, const void* eWhhB, const void* Watt, const void* btag,
  const u32* __restrict__ dflag,
  u16* __restrict__ WihCat, float* __restrict__ bcat, u16* __restrict__ WihH,
  u16* __restrict__ Wcat, float* __restrict__ lbv, u16* __restrict__ WtagP,
  u16* __restrict__ WhhFb, u16* __restrict__ WhhBb, u16* __restrict__ Wattb,
  float* __restrict__ btagf)
{
  bool isf = (*dflag > 64u);
  long i = (long)blockIdx.x * 256 + threadIdx.x;
  if (i < 655360){                       // WihCat [2048][320] (K padded 300->320)
    long n = i / 320, e = i - n*320;
    WihCat[i] = (e < 300)
      ? f2bf(ldin(n < 1024 ? eWihF : eWihB, (size_t)(n & 1023)*300 + e, isf)) : (u16)0;
    return;
  }
  i -= 655360;
  if (i < 2048){ bcat[i] = ldin(i < 1024 ? ebF : ebB, (size_t)(i & 1023), isf); return; }
  i -= 2048;
  if (i < 1048576){                      // WihH [2048][512] = dec_Wih[:,512:1024]
    long n = i >> 9, k = i & 511;
    WihH[i] = f2bf(ldin(dWih, (size_t)n*1028 + 512 + k, isf));
    return;
  }
  i -= 1048576;
  if (i < 2097152){                      // Wcat [2048][1024] = [Wih_ctx | Whh]
    long n = i >> 10, k = i & 1023;
    Wcat[i] = f2bf((k < 512) ? ldin(dWih, (size_t)n*1028 + k, isf)
                             : ldin(dWhh, (size_t)n*512 + (k - 512), isf));
    return;
  }
  i -= 2097152;
  if (i < 8192){                         // lb [4][2048] = dec_b + onehot col
    long l = i >> 11, n = i & 2047;
    lbv[i] = ldin(db, n, isf) + ldin(dWih, (size_t)n*1028 + 1024 + l, isf);
    return;
  }
  i -= 8192;
  if (i < 8192){                         // WtagP [16][512] padded
    long n = i >> 9, k = i & 511;
    WtagP[i] = (n < 9) ? f2bf(ldin(Wtag, (size_t)n*512 + k, isf)) : (u16)0;
    return;
  }
  i -= 8192;
  if (i < 262144){ WhhFb[i] = f2bf(ldin(eWhhF, i, isf)); return; }
  i -= 262144;
  if (i < 262144){ WhhBb[i] = f2bf(ldin(eWhhB, i, isf)); return; }
  i -= 262144;
  if (i < 262144){ Wattb[i] = f2bf(ldin(Watt, i, isf)); return; }
  i -= 262144;
  if (i < 16){ btagf[i] = (i < 9) ? ldin(btag, i, isf) : 0.f; return; }
}

__global__ __launch_bounds__(256) void k_gather(
  const int* __restrict__ seqs, const void* __restrict__ emb,
  const u32* __restrict__ dflag, u16* __restrict__ X)
{
  bool isf = (*dflag > 64u);
  int idx = blockIdx.x * 256 + threadIdx.x;
  if (idx >= 8192*320) return;
  int row = idx / 320, e = idx - row*320;
  int s = row >> 5, b = row & 31;
  int tok = seqs[b*256 + s];
  X[idx] = (e < 300) ? f2bf(ldin(emb, (size_t)tok*300 + e, isf)) : (u16)0;
}

// ---------------- generic bf16 GEMM: C[M,N] = A[M,K] @ B[N,K]^T (+bias) ----------------
// grid = (M/32, N/256), block = 256 (4 waves, each 32x64 tile)

__global__ __launch_bounds__(256) void k_gemm(
  const u16* __restrict__ A, const u16* __restrict__ B, const float* __restrict__ bias,
  u16* __restrict__ C, int M, int N, int K)
{
  int mb = blockIdx.x * 32;
  int wave = threadIdx.x >> 6, lane = threadIdx.x & 63;
  int nb = blockIdx.y * 256 + wave * 64;
  int rlo = lane & 15, klane = (lane >> 4) * 8;
  f32x4 acc[2][4];
  #pragma unroll
  for (int i = 0; i < 2; ++i)
    #pragma unroll
    for (int j = 0; j < 4; ++j) acc[i][j] = (f32x4){0,0,0,0};
  for (int kk = 0; kk < K; kk += 32){
    bf16x8 a0 = *(const bf16x8*)(A + (size_t)(mb + rlo)*K + kk + klane);
    bf16x8 a1 = *(const bf16x8*)(A + (size_t)(mb + 16 + rlo)*K + kk + klane);
    #pragma unroll
    for (int nt = 0; nt < 4; ++nt){
      bf16x8 bv = *(const bf16x8*)(B + (size_t)(nb + nt*16 + rlo)*K + kk + klane);
      acc[0][nt] = mfma16(a0, bv, acc[0][nt]);
      acc[1][nt] = mfma16(a1, bv, acc[1][nt]);
    }
  }
  int rbase = (lane >> 4) * 4;
  #pragma unroll
  for (int mt = 0; mt < 2; ++mt)
    #pragma unroll
    for (int nt = 0; nt < 4; ++nt){
      int col = nb + nt*16 + rlo;
      float badd = bias ? bias[col] : 0.0f;
      #pragma unroll
      for (int r = 0; r < 4; ++r){
        int row = mb + mt*16 + rbase + r;
        C[(size_t)row*N + col] = f2bf(acc[mt][nt][r] + badd);
      }
    }
}

// ---------------- encoder: persistent, 32 WGs (16 per direction) ----------------

__global__ __launch_bounds__(256, 1) void k_encoder(
  const u16* __restrict__ XW, const u16* __restrict__ WhhF, const u16* __restrict__ WhhB,
  u16* __restrict__ hglob, u16* __restrict__ hstate, float* __restrict__ cstate, u32* ctrl)
{
  int wg = blockIdx.x;
  int d = wg >> 4, w = wg & 15;
  const u16* Whh = d ? WhhB : WhhF;
  float* cst = cstate + d * (32*256);
  u32* bar = ctrl + d * 64;
  int tid = threadIdx.x, wave = tid >> 6, lane = tid & 63;
  int cc = lane & 15, klane = (lane >> 4) * 8, rbase = (lane >> 4) * 4;
  __shared__ float g_lds[4][32][16];
  u32 gen = 0;
  for (int t = 0; t < 256; ++t){
    int srow = d ? (255 - t) : t;
    const u16* hr = hstate + (size_t)(d*2 + (t & 1)) * (32*256);
    u16*       hw = hstate + (size_t)(d*2 + ((t & 1) ^ 1)) * (32*256);
    {
      int ncol = wave*256 + w*16 + cc;
      const u16* Brow = Whh + (size_t)ncol*256;
      f32x4 acc0 = {0,0,0,0}, acc1 = {0,0,0,0};
      #pragma unroll
      for (int kk = 0; kk < 256; kk += 32){
        bf16x8 bv = *(const bf16x8*)(Brow + kk + klane);
        bf16x8 a0 = *(const bf16x8*)(hr + cc*256 + kk + klane);
        bf16x8 a1 = *(const bf16x8*)(hr + (cc + 16)*256 + kk + klane);
        acc0 = mfma16(a0, bv, acc0);
        acc1 = mfma16(a1, bv, acc1);
      }
      #pragma unroll
      for (int r = 0; r < 4; ++r){
        g_lds[wave][rbase + r][cc]      = acc0[r];
        g_lds[wave][16 + rbase + r][cc] = acc1[r];
      }
    }
    __syncthreads();
    for (int e = tid; e < 512; e += 256){
      int b_ = e >> 4, jc = e & 15;
      int j = w*16 + jc;
      float pre[4];
      #pragma unroll
      for (int g2 = 0; g2 < 4; ++g2)
        pre[g2] = g_lds[g2][b_][jc] + bf2f(XW[(size_t)(srow*32 + b_)*2048 + d*1024 + g2*256 + j]);
      float iv = sigm(pre[0]), fv = sigm(pre[1]);
      float gv = tanhf(pre[2]), ov = sigm(pre[3]);
      float cv = fv * cst[b_*256 + j] + iv * gv;
      cst[b_*256 + j] = cv;
      float hv = ov * tanhf(cv);
      u16 hb = f2bf(hv);
      hw[b_*256 + j] = hb;
      hglob[(size_t)(srow*32 + b_)*512 + d*256 + j] = hb;
    }
    gen++;
    gbar(bar, gen * 16u);
  }
}

// ---------------- decoder: persistent, 128 WGs, exactly 64KB dynamic LDS ----------------
// WG (b, q): pins h rows [q*64, q*64+64) of batch b in LDS (XOR-swizzled chunks).
// Wh read from global (L2-resident). Small exchanges via global scratch (write-through L1/L2).

__global__ __launch_bounds__(256, 1) void k_decoder(
  const u16* __restrict__ WhG, const u16* __restrict__ hG,
  const u16* __restrict__ Wcat, const u16* __restrict__ Xh, const float* __restrict__ lbv,
  u16* __restrict__ sbuf,        // [2][32][512] bf16 (double-buffered state)
  float* __restrict__ cstate,    // [32][512] f32
  float* __restrict__ ctxp,      // [128][512] f32 partial ctx (per (b,q))
  float2* __restrict__ stats,    // [32][4] (m, den)
  u16* __restrict__ ctxb,        // [32][512] bf16 combined ctx
  float* __restrict__ scg,       // [128][64] per-WG score scratch
  u16* __restrict__ aouts,       // [32768][512] bf16
  u32* bar, u32* flag)
{
  extern __shared__ char smem[];
  u16* h_lds = (u16*)smem;       // 64 rows x 512 bf16 = 65536 B
  int wg = blockIdx.x, tid = threadIdx.x;
  int b = wg >> 2, q = wg & 3;
  int wave = tid >> 6, lane = tid & 63;
  int cc = lane & 15, klane = (lane >> 4) * 8;

  for (int idx = tid; idx < 4096; idx += 256){
    int row = idx >> 6, ch = idx & 63;
    size_t gr = (size_t)((q*64 + row)*32 + b) * 512 + ch*8;
    int dst = row*512 + ((ch ^ (row & 7)) << 3);
    *(uint4*)(h_lds + dst) = *(const uint4*)(hG + gr);
  }
  __syncthreads();

  float* myscg = scg + wg*64;
  u32 gen = 0;
  for (int iter = 0; iter < 1024; ++iter){
    int l = iter >> 8, t = iter & 255;
    const u16* s_read = sbuf + (iter & 1) * 16384;
    u16*       s_write = sbuf + ((iter & 1) ^ 1) * 16384;

    // phase 1: scores (Wh rows from global, s broadcast as MFMA B)
    {
      int jloc = wave*16 + cc;
      const u16* Arow = WhG + (size_t)((q*64 + jloc)*32 + b) * 512;
      const u16* Srow = s_read + b*512;
      f32x4 acc = {0,0,0,0};
      for (int kk = 0; kk < 512; kk += 32){
        bf16x8 av = *(const bf16x8*)(Arow + kk + klane);
        bf16x8 bv = *(const bf16x8*)(Srow + kk + klane);
        acc = mfma16(av, bv, acc);
      }
      if (cc == 0){
        #pragma unroll
        for (int r = 0; r < 4; ++r)
          myscg[wave*16 + (lane >> 4)*4 + r] = acc[r];
      }
    }
    __syncthreads();
    // phase 2: quarter softmax stats (flash-style)
    if (wave == 0){
      float x = myscg[lane];
      float m = x;
      #pragma unroll
      for (int off = 32; off >= 1; off >>= 1) m = fmaxf(m, __shfl_xor(m, off));
      float e = __expf(x - m);
      float den = e;
      #pragma unroll
      for (int off = 32; off >= 1; off >>= 1) den += __shfl_xor(den, off);
      myscg[lane] = e;
      if (lane == 0) stats[b*4 + q] = make_float2(m, den);
    }
    __syncthreads();
    // phase 3: ctx partials (h from LDS), wave owns o-slice of 128, lane owns 2 o's
    {
      int ob = wave*128 + lane*2;
      int ch = ob >> 3, off = ob & 7;
      float a0 = 0.f, a1 = 0.f;
      for (int jj = 0; jj < 64; ++jj){
        float e = myscg[jj];
        u32 hp = *(const u32*)(h_lds + jj*512 + ((ch ^ (jj & 7)) << 3) + off);
        a0 = fmaf(e, bf2f((u16)(hp & 0xFFFFu)), a0);
        a1 = fmaf(e, bf2f((u16)(hp >> 16)), a1);
      }
      ctxp[(size_t)wg*512 + ob]     = a0;
      ctxp[(size_t)wg*512 + ob + 1] = a1;
    }
    gen++; gbar(bar, gen * 128u);   // partials + stats visible

    // phase 4: combine — WG w (<32) builds final ctx for batch w
    if (wg < 32){
      float2 s0 = stats[wg*4+0], s1 = stats[wg*4+1], s2 = stats[wg*4+2], s3 = stats[wg*4+3];
      float m = fmaxf(fmaxf(s0.x, s1.x), fmaxf(s2.x, s3.x));
      float w0 = __expf(s0.x - m), w1 = __expf(s1.x - m), w2 = __expf(s2.x - m), w3 = __expf(s3.x - m);
      float inv = 1.0f / (s0.y*w0 + s1.y*w1 + s2.y*w2 + s3.y*w3);
      const float* cp = ctxp + (size_t)wg*4*512;
      int o = tid*2;
      float v0 = (cp[o]*w0 + cp[512+o]*w1 + cp[1024+o]*w2 + cp[1536+o]*w3) * inv;
      float v1 = (cp[o+1]*w0 + cp[512+o+1]*w1 + cp[1024+o+1]*w2 + cp[1536+o+1]*w3) * inv;
      ctxb[wg*512 + o]     = f2bf(v0);
      ctxb[wg*512 + o + 1] = f2bf(v1);
      __threadfence();
      __syncthreads();
      if (tid == 0) __hip_atomic_fetch_add(flag, 1u, __ATOMIC_RELEASE, __HIP_MEMORY_SCOPE_AGENT);
    }

    // phase 5: gate GEMM — wave owns j = wg*4+wave, full K; gates duplicated over B cols
    {
      int j = wg*4 + wave;
      const u16* Brow = Wcat + (size_t)((cc & 3)*512 + j) * 1024;
      f32x4 acc0 = {0,0,0,0}, acc1 = {0,0,0,0};
      for (int kk = 0; kk < 512; kk += 32){   // s-half (K 512..1023), no wait needed
        bf16x8 bv = *(const bf16x8*)(Brow + 512 + kk + klane);
        bf16x8 a0 = *(const bf16x8*)(s_read + cc*512 + kk + klane);
        bf16x8 a1 = *(const bf16x8*)(s_read + (cc + 16)*512 + kk + klane);
        acc0 = mfma16(a0, bv, acc0);
        acc1 = mfma16(a1, bv, acc1);
      }
      {   // wait for all 32 combined ctx rows
        u32 tgt = 32u * (u32)(iter + 1);
        u32 cur;
        do {
          u32 v = 0;
          if (lane == 0) v = __hip_atomic_load(flag, __ATOMIC_RELAXED, __HIP_MEMORY_SCOPE_AGENT);
          cur = __shfl(v, 0);
          if (cur < tgt) __builtin_amdgcn_s_sleep(1);
        } while (cur < tgt);
        if (lane == 0) (void)__hip_atomic_load(flag, __ATOMIC_ACQUIRE, __HIP_MEMORY_SCOPE_AGENT);
        __builtin_amdgcn_sched_barrier(0);
      }
      for (int kk = 0; kk < 512; kk += 32){   // ctx-half (K 0..511)
        bf16x8 bv = *(const bf16x8*)(Brow + kk + klane);
        bf16x8 a0 = *(const bf16x8*)(ctxb + cc*512 + kk + klane);
        bf16x8 a1 = *(const bf16x8*)(ctxb + (cc + 16)*512 + kk + klane);
        acc0 = mfma16(a0, bv, acc0);
        acc1 = mfma16(a1, bv, acc1);
      }
      // in-wave exchange: lane x<32 gathers 4 gate values for batch b_=x
      int b_ = lane & 31;
      float pre[4];
      #pragma unroll
      for (int g2 = 0; g2 < 4; ++g2){
        int src = (((b_ & 15) >> 2) << 4) + g2;
        float v = 0.f;
        #pragma unroll
        for (int r = 0; r < 4; ++r){
          float t0 = __shfl(acc0[r], src);
          float t1 = __shfl(acc1[r], src);
          if ((b_ & 3) == r) v = (b_ < 16) ? t0 : t1;
        }
        pre[g2] = v + bf2f(Xh[(size_t)(t*32 + b_)*2048 + g2*512 + j]) + lbv[l*2048 + g2*512 + j];
      }
      if (lane < 32){
        float iv = sigm(pre[0]), fv = sigm(pre[1]);
        float gv = tanhf(pre[2]), ov = sigm(pre[3]);
        float cv = fv * cstate[b_*512 + j] + iv * gv;
        cstate[b_*512 + j] = cv;
        float hv = ov * tanhf(cv);
        u16 hb = f2bf(hv);
        s_write[b_*512 + j] = hb;
        aouts[(size_t)((l*256 + t)*32 + b_)*512 + j] = hb;
      }
    }
    gen++; gbar(bar, gen * 128u);   // new state visible for next step
  }
}

// ---------------- tag projection: out = all_outs @ W_tag^T + b_tag ----------------

__global__ __launch_bounds__(256) void k_tag(
  const u16* __restrict__ aouts, const u16* __restrict__ WtagP, const float* __restrict__ btagf,
  const u32* __restrict__ dflag, void* __restrict__ out)
{
  bool isf = (*dflag > 64u);
  int wave = threadIdx.x >> 6, lane = threadIdx.x & 63;
  int mb = (blockIdx.x * 4 + wave) * 16;
  int cc = lane & 15, klane = (lane >> 4) * 8;
  f32x4 acc = {0,0,0,0};
  const u16* Arow = aouts + (size_t)(mb + cc)*512;
  const u16* Brow = WtagP + cc*512;
  #pragma unroll
  for (int kk = 0; kk < 512; kk += 32){
    bf16x8 av = *(const bf16x8*)(Arow + kk + klane);
    bf16x8 bv = *(const bf16x8*)(Brow + kk + klane);
    acc = mfma16(av, bv, acc);
  }
  int rbase = (lane >> 4) * 4;
  if (cc < 9){
    float bt = btagf[cc];
    #pragma unroll
    for (int r = 0; r < 4; ++r){
      int row = mb + rbase + r;
      float v = acc[r] + bt;
      if (isf) ((float*)out)[(size_t)row*9 + cc] = v;
      else     ((u16*)out)[(size_t)row*9 + cc] = f2bf(v);
    }
  }
}

// ---------------- host ----------------

extern "C" void kernel_launch(void* const* d_in, const int* in_sizes, int n_in,
                              void* d_out, int out_size, void* d_ws, size_t ws_size,
                              hipStream_t stream)
{
  (void)in_sizes; (void)n_in; (void)out_size;
  if (ws_size < 98953344ull) return;   // workspace guard (out stays zero -> distinguishable)

  const int* seqs = (const int*)d_in[0];

  char* ws = (char*)d_ws;
  u32*    ctrl   = (u32*)(ws + 0);          // barF@0 barB@64 barDec@128 flag@192 dflag@240
  u32*    dflag  = ctrl + 240;
  float*  dec_c  = (float*)(ws + 1024);     // [32][512] f32
  u16*    sbuf   = (u16*)(ws + 66560);      // [2][32][512]
  u16*    hstate = (u16*)(ws + 132096);     // [4][32][256]
  float*  enc_c  = (float*)(ws + 197632);   // [2][32][256]
  float2* stats  = (float2*)(ws + 263168);  // [32][4]
  float*  ctxp   = (float*)(ws + 264192);   // [128][512]
  u16*    ctxb   = (u16*)(ws + 526336);     // [32][512]
  float*  scg    = (float*)(ws + 559104);   // [128][64]
  // memset end = 591872
  u16*    WihCat = (u16*)(ws + 591872);     // [2048][320]
  float*  bcat   = (float*)(ws + 1902592);  // [2048]
  u16*    WihH   = (u16*)(ws + 1910784);    // [2048][512]
  u16*    Wcat   = (u16*)(ws + 4007936);    // [2048][1024]
  float*  lbv    = (float*)(ws + 8202240);  // [4][2048]
  u16*    WtagP  = (u16*)(ws + 8235008);    // [16][512]
  u16*    WhhFb  = (u16*)(ws + 8251392);    // [1024][256]
  u16*    WhhBb  = (u16*)(ws + 8775680);    // [1024][256]
  u16*    Wattb  = (u16*)(ws + 9299968);    // [512][512]
  float*  btagf  = (float*)(ws + 9824256);  // [16]
  u16*    X      = (u16*)(ws + 9824384);    // [8192][320]
  u16*    XWXh   = (u16*)(ws + 15067264);   // [8192][2048] XW, later aliased as Xh
  u16*    hglob  = (u16*)(ws + 48621696);   // [8192][512]
  u16*    Whb    = (u16*)(ws + 57010304);   // [8192][512]
  u16*    aouts  = (u16*)(ws + 65398912);   // [32768][512]

  hipMemsetAsync(d_ws, 0, 591872, stream);

  k_detect<<<1, 256, 0, stream>>>((const u32*)d_in[1], dflag);
  k_pack<<<17993, 256, 0, stream>>>(
      d_in[2], d_in[5], d_in[4], d_in[7], d_in[9], d_in[10], d_in[11], d_in[12],
      d_in[3], d_in[6], d_in[8], d_in[13], dflag,
      WihCat, bcat, WihH, Wcat, lbv, WtagP, WhhFb, WhhBb, Wattb, btagf);
  k_gather<<<10240, 256, 0, stream>>>(seqs, d_in[1], dflag, X);
  // XW = X @ [Wih_f; Wih_b]^T + [b_f; b_b]
  k_gemm<<<dim3(256, 8), 256, 0, stream>>>(X, WihCat, bcat, XWXh, 8192, 2048, 320);
  k_encoder<<<32, 256, 0, stream>>>(XWXh, WhhFb, WhhBb, hglob, hstate, enc_c, ctrl);
  // Wh = h @ W_att^T ; Xh = h @ Wih_h^T (Xh aliases XW: XW dead after encoder)
  k_gemm<<<dim3(256, 2), 256, 0, stream>>>(hglob, Wattb, nullptr, Whb, 8192, 512, 512);
  k_gemm<<<dim3(256, 8), 256, 0, stream>>>(hglob, WihH, nullptr, XWXh, 8192, 2048, 512);

  k_decoder<<<128, 256, 65536, stream>>>(Whb, hglob, Wcat, XWXh, lbv,
                                         sbuf, dec_c, ctxp, stats, ctxb, scg, aouts,
                                         ctrl + 128, ctrl + 192);
  k_tag<<<512, 256, 0, stream>>>(aouts, WtagP, btagf, dflag, d_out);
}

// Round 3
// 26470.639 us; speedup vs baseline: 1.6758x; 1.6758x over previous
//
#include <hip/hip_runtime.h>
#include <cstdint>
#include <cstddef>

using u16 = unsigned short;
using u32 = unsigned int;

typedef __attribute__((ext_vector_type(8))) __bf16 bf16x8;
typedef __attribute__((ext_vector_type(4))) float f32x4;

__device__ __forceinline__ float bf2f(u16 u){
  union { u32 i; float f; } v; v.i = ((u32)u) << 16; return v.f;
}
__device__ __forceinline__ u16 f2bf(float f){
  union { float f; u32 i; } v; v.f = f;
  return (u16)((v.i + 0x7FFFu + ((v.i >> 16) & 1u)) >> 16);
}
__device__ __forceinline__ float sigm(float x){ return 1.0f / (1.0f + __expf(-x)); }
__device__ __forceinline__ f32x4 mfma16(bf16x8 a, bf16x8 b, f32x4 c){
  return __builtin_amdgcn_mfma_f32_16x16x32_bf16(a, b, c, 0, 0, 0);
}
__device__ __forceinline__ float ldin(const void* p, size_t i, bool f){
  return f ? ((const float*)p)[i] : bf2f(((const u16*)p)[i]);
}

// device-scope barrier (full): monotonic counter, target = gen * nwg
__device__ __forceinline__ void gbar(u32* bar, u32 target){
  __syncthreads();
  if (threadIdx.x == 0){
    __hip_atomic_fetch_add(bar, 1u, __ATOMIC_ACQ_REL, __HIP_MEMORY_SCOPE_AGENT);
    while (__hip_atomic_load(bar, __ATOMIC_RELAXED, __HIP_MEMORY_SCOPE_AGENT) < target)
      __builtin_amdgcn_s_sleep(2);
    (void)__hip_atomic_load(bar, __ATOMIC_ACQUIRE, __HIP_MEMORY_SCOPE_AGENT);
  }
  __syncthreads();
}

// ---------------- dtype detection ----------------
__global__ __launch_bounds__(256) void k_detect(const u32* __restrict__ embw, u32* __restrict__ dflag){
  int tid = threadIdx.x;
  u32 cnt = 0;
  for (int t = 0; t < 32; ++t){
    u32 w = embw[t*256 + tid];
    u32 e = (w >> 7) & 0xFFu;
    cnt += (e >= 0xC0u) ? 1u : 0u;
  }
  atomicAdd(dflag, cnt);
}

// ---------------- pack (weights -> bf16/f32 in ws) ----------------

__global__ __launch_bounds__(256) void k_pack(
  const void* eWihF, const void* eWihB, const void* ebF, const void* ebB,
  const void* dWih, const void* dWhh, const void* db, const void* Wtag,
  const void* eWhhF, const void* eWhhB, const void* Watt, const void* btag,
  const u32* __restrict__ dflag,
  u16* __restrict__ WihCat, float* __restrict__ bcat, u16* __restrict__ WihH,
  u16* __restrict__ Wf, float* __restrict__ lbv, u16* __restrict__ WtagP,
  u16* __restrict__ WhhFb, u16* __restrict__ WhhBb, u16* __restrict__ Wattb,
  float* __restrict__ btagf)
{
  bool isf = (*dflag > 64u);
  long i = (long)blockIdx.x * 256 + threadIdx.x;
  if (i < 655360){                       // WihCat [2048][320] (K padded 300->320)
    long n = i / 320, e = i - n*320;
    WihCat[i] = (e < 300)
      ? f2bf(ldin(n < 1024 ? eWihF : eWihB, (size_t)(n & 1023)*300 + e, isf)) : (u16)0;
    return;
  }
  i -= 655360;
  if (i < 2048){ bcat[i] = ldin(i < 1024 ? ebF : ebB, (size_t)(i & 1023), isf); return; }
  i -= 2048;
  if (i < 1048576){                      // WihH [2048][512] = dec_Wih[:,512:1024]
    long n = i >> 9, k = i & 511;
    WihH[i] = f2bf(ldin(dWih, (size_t)n*1028 + 512 + k, isf));
    return;
  }
  i -= 1048576;
  if (i < 2097152){                      // Wf: gate weights in MFMA A-fragment layout
    long e  = i & 7;
    long ln = (i >> 3) & 63;
    long kt = (i >> 9) & 31;
    long rt = (i >> 14) & 3;
    long wgi = i >> 16;
    long n = rt*512 + wgi*16 + (ln & 15);
    long k = kt*32 + (ln >> 4)*8 + e;
    Wf[i] = f2bf((k < 512) ? ldin(dWih, (size_t)n*1028 + k, isf)
                           : ldin(dWhh, (size_t)n*512 + (k - 512), isf));
    return;
  }
  i -= 2097152;
  if (i < 8192){                         // lb [4][2048] = dec_b + onehot col
    long l = i >> 11, n = i & 2047;
    lbv[i] = ldin(db, n, isf) + ldin(dWih, (size_t)n*1028 + 1024 + l, isf);
    return;
  }
  i -= 8192;
  if (i < 8192){                         // WtagP [16][512] padded
    long n = i >> 9, k = i & 511;
    WtagP[i] = (n < 9) ? f2bf(ldin(Wtag, (size_t)n*512 + k, isf)) : (u16)0;
    return;
  }
  i -= 8192;
  if (i < 262144){ WhhFb[i] = f2bf(ldin(eWhhF, i, isf)); return; }
  i -= 262144;
  if (i < 262144){ WhhBb[i] = f2bf(ldin(eWhhB, i, isf)); return; }
  i -= 262144;
  if (i < 262144){ Wattb[i] = f2bf(ldin(Watt, i, isf)); return; }
  i -= 262144;
  if (i < 16){ btagf[i] = (i < 9) ? ldin(btag, i, isf) : 0.f; return; }
}

__global__ __launch_bounds__(256) void k_gather(
  const int* __restrict__ seqs, const void* __restrict__ emb,
  const u32* __restrict__ dflag, u16* __restrict__ X)
{
  bool isf = (*dflag > 64u);
  int idx = blockIdx.x * 256 + threadIdx.x;
  if (idx >= 8192*320) return;
  int row = idx / 320, e = idx - row*320;
  int s = row >> 5, b = row & 31;
  int tok = seqs[b*256 + s];
  X[idx] = (e < 300) ? f2bf(ldin(emb, (size_t)tok*300 + e, isf)) : (u16)0;
}

// ---------------- generic bf16 GEMM: C[M,N] = A[M,K] @ B[N,K]^T (+bias) ----------------

__global__ __launch_bounds__(256) void k_gemm(
  const u16* __restrict__ A, const u16* __restrict__ B, const float* __restrict__ bias,
  u16* __restrict__ C, int M, int N, int K)
{
  int mb = blockIdx.x * 32;
  int wave = threadIdx.x >> 6, lane = threadIdx.x & 63;
  int nb = blockIdx.y * 256 + wave * 64;
  int rlo = lane & 15, klane = (lane >> 4) * 8;
  f32x4 acc[2][4];
  #pragma unroll
  for (int i = 0; i < 2; ++i)
    #pragma unroll
    for (int j = 0; j < 4; ++j) acc[i][j] = (f32x4){0,0,0,0};
  for (int kk = 0; kk < K; kk += 32){
    bf16x8 a0 = *(const bf16x8*)(A + (size_t)(mb + rlo)*K + kk + klane);
    bf16x8 a1 = *(const bf16x8*)(A + (size_t)(mb + 16 + rlo)*K + kk + klane);
    #pragma unroll
    for (int nt = 0; nt < 4; ++nt){
      bf16x8 bv = *(const bf16x8*)(B + (size_t)(nb + nt*16 + rlo)*K + kk + klane);
      acc[0][nt] = mfma16(a0, bv, acc[0][nt]);
      acc[1][nt] = mfma16(a1, bv, acc[1][nt]);
    }
  }
  int rbase = (lane >> 4) * 4;
  #pragma unroll
  for (int mt = 0; mt < 2; ++mt)
    #pragma unroll
    for (int nt = 0; nt < 4; ++nt){
      int col = nb + nt*16 + rlo;
      float badd = bias ? bias[col] : 0.0f;
      #pragma unroll
      for (int r = 0; r < 4; ++r){
        int row = mb + mt*16 + rbase + r;
        C[(size_t)row*N + col] = f2bf(acc[mt][nt][r] + badd);
      }
    }
}

// ---------------- transpose h -> hT[b][d][j] ----------------

__global__ __launch_bounds__(256) void k_transp(const u16* __restrict__ hglob, u16* __restrict__ hT)
{
  __shared__ u16 tile_t[64][264];     // [d-local][j], padded for 16B-aligned rows
  int b = blockIdx.x >> 3, d0 = (blockIdx.x & 7) * 64;
  int t = threadIdx.x;
  for (int rr = 0; rr < 16; ++rr){
    int c = rr*256 + t;               // c in [0,4096): j = c>>4, dq = (c&15)*4
    int j = c >> 4, dq = (c & 15) * 4;
    ushort4 ld = *(const ushort4*)(hglob + ((size_t)(j*32 + b)*512 + d0 + dq));
    tile_t[dq + 0][j] = ld.x;
    tile_t[dq + 1][j] = ld.y;
    tile_t[dq + 2][j] = ld.z;
    tile_t[dq + 3][j] = ld.w;
  }
  __syncthreads();
  for (int rr = 0; rr < 8; ++rr){
    int c = rr*256 + t;               // c in [0,2048): d = c>>5, jq = (c&31)*8
    int d = c >> 5, jq = (c & 31) * 8;
    *(uint4*)(hT + ((size_t)(b*512 + d0 + d)*256 + jq)) = *(const uint4*)&tile_t[d][jq];
  }
}

// ---------------- encoder: persistent, 32 WGs (16 per direction) ----------------

__global__ __launch_bounds__(256, 1) void k_encoder(
  const u16* __restrict__ XW, const u16* __restrict__ WhhF, const u16* __restrict__ WhhB,
  u16* __restrict__ hglob, u16* __restrict__ hstate, float* __restrict__ cstate, u32* ctrl)
{
  int wg = blockIdx.x;
  int d = wg >> 4, w = wg & 15;
  const u16* Whh = d ? WhhB : WhhF;
  float* cst = cstate + d * (32*256);
  u32* bar = ctrl + d * 64;
  int tid = threadIdx.x, wave = tid >> 6, lane = tid & 63;
  int cc = lane & 15, klane = (lane >> 4) * 8, rbase = (lane >> 4) * 4;
  __shared__ float g_lds[4][32][16];
  u32 gen = 0;
  for (int t = 0; t < 256; ++t){
    int srow = d ? (255 - t) : t;
    const u16* hr = hstate + (size_t)(d*2 + (t & 1)) * (32*256);
    u16*       hw = hstate + (size_t)(d*2 + ((t & 1) ^ 1)) * (32*256);
    {
      int ncol = wave*256 + w*16 + cc;
      const u16* Brow = Whh + (size_t)ncol*256;
      f32x4 acc0 = {0,0,0,0}, acc1 = {0,0,0,0};
      #pragma unroll
      for (int kk = 0; kk < 256; kk += 32){
        bf16x8 bv = *(const bf16x8*)(Brow + kk + klane);
        bf16x8 a0 = *(const bf16x8*)(hr + cc*256 + kk + klane);
        bf16x8 a1 = *(const bf16x8*)(hr + (cc + 16)*256 + kk + klane);
        acc0 = mfma16(a0, bv, acc0);
        acc1 = mfma16(a1, bv, acc1);
      }
      #pragma unroll
      for (int r = 0; r < 4; ++r){
        g_lds[wave][rbase + r][cc]      = acc0[r];
        g_lds[wave][16 + rbase + r][cc] = acc1[r];
      }
    }
    __syncthreads();
    for (int e = tid; e < 512; e += 256){
      int b_ = e >> 4, jc = e & 15;
      int j = w*16 + jc;
      float pre[4];
      #pragma unroll
      for (int g2 = 0; g2 < 4; ++g2)
        pre[g2] = g_lds[g2][b_][jc] + bf2f(XW[(size_t)(srow*32 + b_)*2048 + d*1024 + g2*256 + j]);
      float iv = sigm(pre[0]), fv = sigm(pre[1]);
      float gv = tanhf(pre[2]), ov = sigm(pre[3]);
      float cv = fv * cst[b_*256 + j] + iv * gv;
      cst[b_*256 + j] = cv;
      float hv = ov * tanhf(cv);
      u16 hb = f2bf(hv);
      hw[b_*256 + j] = hb;
      hglob[(size_t)(srow*32 + b_)*512 + d*256 + j] = hb;
    }
    gen++;
    gbar(bar, gen * 16u);
  }
}

// ---------------- decoder: persistent, 32 WGs x 512 threads, 2 barriers/step ----------------
// WG b: full attention for batch b (Wh pinned in VGPRs, hT from L2)
//       + gate-output slice dims [b*16, b*16+16) x 4 gates for ALL batches (Wf streamed).

__global__ __launch_bounds__(512, 1) void k_decoder(
  const u16* __restrict__ Whb, const u16* __restrict__ hT,
  const u16* __restrict__ Wf, const u16* __restrict__ Xh, const float* __restrict__ lbv,
  u16* __restrict__ Ain,          // [2][32][1024] bf16: [b][0:512)=ctx, [512:1024)=s
  u16* __restrict__ aouts,        // [32768][512] bf16
  u32* bar1, u32* bar2)
{
  __shared__ __align__(16) u16 s_stage[512];
  __shared__ float score_lds[256];
  __shared__ __align__(16) u16 att_bf[256];
  __shared__ float gbuf[4][16][33];
  __shared__ float c_lds[512];
  const int wg = blockIdx.x, tid = threadIdx.x;
  const int wave = tid >> 6, lane = tid & 63;
  const int q = lane >> 4, cc = lane & 15;
  c_lds[tid] = 0.0f;

  // pin Wh_b A-fragments in VGPRs: wave holds score rows [wave*32, wave*32+32)
  bf16x8 wh[2][16];
  #pragma unroll
  for (int rt = 0; rt < 2; ++rt)
    #pragma unroll
    for (int kt = 0; kt < 16; ++kt){
      int row = wave*32 + rt*16 + cc;
      wh[rt][kt] = *(const bf16x8*)(Whb + ((size_t)(row*32 + wg))*512 + kt*32 + q*8);
    }
  const int grt = wave >> 1, gct = wave & 1;          // gate tile (rt, ct) per wave
  const int bcol = gct*16 + cc;
  const u16* WfW = Wf + (size_t)wg*65536;
  __syncthreads();

  for (int iter = 0; iter < 1024; ++iter){
    const int l = iter >> 8, t = iter & 255;
    u16* AinC = Ain + (iter & 1)*32768;
    u16* AinN = Ain + ((iter & 1) ^ 1)*32768;

    // stage s_b
    if (tid < 64) ((uint4*)s_stage)[tid] = ((const uint4*)(AinC + wg*1024 + 512))[tid];
    __syncthreads();

    // scores: MFMA(Wh-VGPR, s broadcast)
    f32x4 sa0 = {0,0,0,0}, sa1 = {0,0,0,0};
    #pragma unroll
    for (int kt = 0; kt < 16; ++kt){
      bf16x8 sv = *(const bf16x8*)(s_stage + kt*32 + q*8);
      sa0 = mfma16(wh[0][kt], sv, sa0);
      sa1 = mfma16(wh[1][kt], sv, sa1);
    }
    if (cc == 0){
      #pragma unroll
      for (int r = 0; r < 4; ++r){
        score_lds[wave*32      + q*4 + r] = sa0[r];
        score_lds[wave*32 + 16 + q*4 + r] = sa1[r];
      }
    }
    __syncthreads();

    // softmax (wave 0, 4 scores/lane)
    if (wave == 0){
      float x0 = score_lds[lane*4+0], x1 = score_lds[lane*4+1];
      float x2 = score_lds[lane*4+2], x3 = score_lds[lane*4+3];
      float m = fmaxf(fmaxf(x0,x1), fmaxf(x2,x3));
      #pragma unroll
      for (int off = 32; off >= 1; off >>= 1) m = fmaxf(m, __shfl_xor(m, off));
      float e0 = __expf(x0-m), e1 = __expf(x1-m), e2 = __expf(x2-m), e3 = __expf(x3-m);
      float s = e0+e1+e2+e3;
      #pragma unroll
      for (int off = 32; off >= 1; off >>= 1) s += __shfl_xor(s, off);
      float inv = 1.0f / s;
      att_bf[lane*4+0] = f2bf(e0*inv);
      att_bf[lane*4+1] = f2bf(e1*inv);
      att_bf[lane*4+2] = f2bf(e2*inv);
      att_bf[lane*4+3] = f2bf(e3*inv);
    }
    __syncthreads();

    // ctx: MFMA(att row-0, hT B-frags). wave owns dims [wave*64, wave*64+64)
    f32x4 ca0 = {0,0,0,0}, ca1 = {0,0,0,0}, ca2 = {0,0,0,0}, ca3 = {0,0,0,0};
    #pragma unroll
    for (int jt = 0; jt < 8; ++jt){
      uint4 au = {0,0,0,0};
      if (cc == 0) au = *(const uint4*)(att_bf + jt*32 + q*8);
      bf16x8 af = *(bf16x8*)&au;
      const u16* hb = hT + ((size_t)(wg*512 + wave*64 + cc))*256 + jt*32 + q*8;
      ca0 = mfma16(af, *(const bf16x8*)(hb +    0*256), ca0);
      ca1 = mfma16(af, *(const bf16x8*)(hb +   16*256), ca1);
      ca2 = mfma16(af, *(const bf16x8*)(hb +   32*256), ca2);
      ca3 = mfma16(af, *(const bf16x8*)(hb +   48*256), ca3);
    }
    if (lane < 16){
      AinC[wg*1024 + wave*64 +  0 + lane] = f2bf(ca0[0]);
      AinC[wg*1024 + wave*64 + 16 + lane] = f2bf(ca1[0]);
      AinC[wg*1024 + wave*64 + 32 + lane] = f2bf(ca2[0]);
      AinC[wg*1024 + wave*64 + 48 + lane] = f2bf(ca3[0]);
    }
    __syncthreads();                   // drains vmcnt for whole WG
    if (tid == 0)
      __hip_atomic_fetch_add(bar2, 1u, __ATOMIC_ACQ_REL, __HIP_MEMORY_SCOPE_AGENT);

    // gate s-half (K 512..1023) — overlaps other WGs' ctx writes
    f32x4 ga = {0,0,0,0};
    #pragma unroll
    for (int kt = 16; kt < 32; ++kt){
      bf16x8 wa = *(const bf16x8*)(WfW + ((grt*32 + kt)*64 + lane)*8);
      bf16x8 av = *(const bf16x8*)(AinC + bcol*1024 + kt*32 + q*8);
      ga = mfma16(wa, av, ga);
    }
    // wait bar2 (all ctx visible)
    if (tid == 0){
      const u32 tgt = 32u*(u32)(iter+1);
      while (__hip_atomic_load(bar2, __ATOMIC_RELAXED, __HIP_MEMORY_SCOPE_AGENT) < tgt)
        __builtin_amdgcn_s_sleep(2);
      (void)__hip_atomic_load(bar2, __ATOMIC_ACQUIRE, __HIP_MEMORY_SCOPE_AGENT);
    }
    __syncthreads();
    // gate ctx-half (K 0..511)
    #pragma unroll
    for (int kt = 0; kt < 16; ++kt){
      bf16x8 wa = *(const bf16x8*)(WfW + ((grt*32 + kt)*64 + lane)*8);
      bf16x8 av = *(const bf16x8*)(AinC + bcol*1024 + kt*32 + q*8);
      ga = mfma16(wa, av, ga);
    }
    #pragma unroll
    for (int r = 0; r < 4; ++r) gbuf[grt][q*4 + r][bcol] = ga[r];
    __syncthreads();

    // pointwise: thread = (b_, dd); this WG owns h-dims [wg*16, wg*16+16)
    {
      const int b_ = tid >> 4, dd = tid & 15;
      const int gj = wg*16 + dd;
      float pre[4];
      #pragma unroll
      for (int g = 0; g < 4; ++g){
        int n = g*512 + gj;
        pre[g] = gbuf[g][dd][b_] + bf2f(Xh[(size_t)(t*32 + b_)*2048 + n]) + lbv[l*2048 + n];
      }
      float iv = sigm(pre[0]), fv = sigm(pre[1]);
      float gv = tanhf(pre[2]), ov = sigm(pre[3]);
      float cv = fv * c_lds[tid] + iv * gv;
      c_lds[tid] = cv;
      u16 hb = f2bf(ov * tanhf(cv));
      AinN[b_*1024 + 512 + gj] = hb;
      aouts[(size_t)((l*256 + t)*32 + b_)*512 + gj] = hb;
    }
    __syncthreads();                   // drains vmcnt
    if (tid == 0){
      __hip_atomic_fetch_add(bar1, 1u, __ATOMIC_ACQ_REL, __HIP_MEMORY_SCOPE_AGENT);
      const u32 tgt = 32u*(u32)(iter+1);
      while (__hip_atomic_load(bar1, __ATOMIC_RELAXED, __HIP_MEMORY_SCOPE_AGENT) < tgt)
        __builtin_amdgcn_s_sleep(2);
      (void)__hip_atomic_load(bar1, __ATOMIC_ACQUIRE, __HIP_MEMORY_SCOPE_AGENT);
    }
    __syncthreads();
  }
}

// ---------------- tag projection ----------------

__global__ __launch_bounds__(256) void k_tag(
  const u16* __restrict__ aouts, const u16* __restrict__ WtagP, const float* __restrict__ btagf,
  const u32* __restrict__ dflag, void* __restrict__ out)
{
  bool isf = (*dflag > 64u);
  int wave = threadIdx.x >> 6, lane = threadIdx.x & 63;
  int mb = (blockIdx.x * 4 + wave) * 16;
  int cc = lane & 15, klane = (lane >> 4) * 8;
  f32x4 acc = {0,0,0,0};
  const u16* Arow = aouts + (size_t)(mb + cc)*512;
  const u16* Brow = WtagP + cc*512;
  #pragma unroll
  for (int kk = 0; kk < 512; kk += 32){
    bf16x8 av = *(const bf16x8*)(Arow + kk + klane);
    bf16x8 bv = *(const bf16x8*)(Brow + kk + klane);
    acc = mfma16(av, bv, acc);
  }
  int rbase = (lane >> 4) * 4;
  if (cc < 9){
    float bt = btagf[cc];
    #pragma unroll
    for (int r = 0; r < 4; ++r){
      int row = mb + rbase + r;
      float v = acc[r] + bt;
      if (isf) ((float*)out)[(size_t)row*9 + cc] = v;
      else     ((u16*)out)[(size_t)row*9 + cc] = f2bf(v);
    }
  }
}

// ---------------- host ----------------

extern "C" void kernel_launch(void* const* d_in, const int* in_sizes, int n_in,
                              void* d_out, int out_size, void* d_ws, size_t ws_size,
                              hipStream_t stream)
{
  (void)in_sizes; (void)n_in; (void)out_size;
  if (ws_size < 98625536ull) return;

  const int* seqs = (const int*)d_in[0];

  char* ws = (char*)d_ws;
  u32*    ctrl   = (u32*)(ws + 0);          // barEncF@0 barEncB@64 barDec1@128 barDec2@160 dflag@240
  u32*    dflag  = ctrl + 240;
  u16*    Ain    = (u16*)(ws + 1024);       // [2][32][1024] bf16
  u16*    hstate = (u16*)(ws + 132096);     // [4][32][256]
  float*  enc_c  = (float*)(ws + 197632);   // [2][32][256]
  // memset end = 263168
  u16*    WihCat = (u16*)(ws + 263168);     // [2048][320]
  float*  bcat   = (float*)(ws + 1573888);  // [2048]
  u16*    WihH   = (u16*)(ws + 1582080);    // [2048][512]
  u16*    Wf     = (u16*)(ws + 3679232);    // [32][4][32][64][8] fragment layout (4MB)
  float*  lbv    = (float*)(ws + 7873536);  // [4][2048]
  u16*    WtagP  = (u16*)(ws + 7906304);    // [16][512]
  u16*    WhhFb  = (u16*)(ws + 7922688);    // [1024][256]
  u16*    WhhBb  = (u16*)(ws + 8446976);    // [1024][256]
  u16*    Wattb  = (u16*)(ws + 8971264);    // [512][512]
  float*  btagf  = (float*)(ws + 9495552);  // [16]
  u16*    X      = (u16*)(ws + 9496576);    // [8192][320]
  u16*    XWXh   = (u16*)(ws + 14739456);   // [8192][2048] XW, later Xh (aliased)
  u16*    aouts  = (u16*)(ws + 48293888);   // [32768][512]; first 8.4MB doubles as hglob pre-decoder
  u16*    hglob  = (u16*)(ws + 48293888);   // alias (dead before decoder writes aouts)
  u16*    hT     = (u16*)(ws + 81848320);   // [32][512][256]
  u16*    Whb    = (u16*)(ws + 90236928);   // [8192][512]

  hipMemsetAsync(d_ws, 0, 263168, stream);

  k_detect<<<1, 256, 0, stream>>>((const u32*)d_in[1], dflag);
  k_pack<<<17993, 256, 0, stream>>>(
      d_in[2], d_in[5], d_in[4], d_in[7], d_in[9], d_in[10], d_in[11], d_in[12],
      d_in[3], d_in[6], d_in[8], d_in[13], dflag,
      WihCat, bcat, WihH, Wf, lbv, WtagP, WhhFb, WhhBb, Wattb, btagf);
  k_gather<<<10240, 256, 0, stream>>>(seqs, d_in[1], dflag, X);
  // XW = X @ [Wih_f; Wih_b]^T + bias
  k_gemm<<<dim3(256, 8), 256, 0, stream>>>(X, WihCat, bcat, XWXh, 8192, 2048, 320);
  k_encoder<<<32, 256, 0, stream>>>(XWXh, WhhFb, WhhBb, hglob, hstate, enc_c, ctrl);
  // Wh = h @ W_att^T ; Xh = h @ Wih_h^T (Xh aliases XW)
  k_gemm<<<dim3(256, 2), 256, 0, stream>>>(hglob, Wattb, nullptr, Whb, 8192, 512, 512);
  k_gemm<<<dim3(256, 8), 256, 0, stream>>>(hglob, WihH, nullptr, XWXh, 8192, 2048, 512);
  k_transp<<<256, 256, 0, stream>>>(hglob, hT);

  k_decoder<<<32, 512, 0, stream>>>(Whb, hT, Wf, XWXh, lbv, Ain, aouts,
                                    ctrl + 128, ctrl + 160);
  k_tag<<<512, 256, 0, stream>>>(aouts, WtagP, btagf, dflag, d_out);
}

// Round 4
// 21517.992 us; speedup vs baseline: 2.0615x; 1.2302x over previous
//
#include <hip/hip_runtime.h>
#include <cstdint>
#include <cstddef>

using u16 = unsigned short;
using u32 = unsigned int;

typedef __attribute__((ext_vector_type(8))) __bf16 bf16x8;
typedef __attribute__((ext_vector_type(4))) float f32x4;

__device__ __forceinline__ float bf2f(u16 u){
  union { u32 i; float f; } v; v.i = ((u32)u) << 16; return v.f;
}
__device__ __forceinline__ u16 f2bf(float f){
  union { float f; u32 i; } v; v.f = f;
  return (u16)((v.i + 0x7FFFu + ((v.i >> 16) & 1u)) >> 16);
}
__device__ __forceinline__ float sigm(float x){ return 1.0f / (1.0f + __expf(-x)); }
__device__ __forceinline__ f32x4 mfma16(bf16x8 a, bf16x8 b, f32x4 c){
  return __builtin_amdgcn_mfma_f32_16x16x32_bf16(a, b, c, 0, 0, 0);
}
__device__ __forceinline__ float ldin(const void* p, size_t i, bool f){
  return f ? ((const float*)p)[i] : bf2f(((const u16*)p)[i]);
}

// ---- coherence-point (MALL) access primitives: no L1/L2 allocation, no fences ----
__device__ __forceinline__ uint4 ldx4_cg(const u16* p){
  uint4 r;
  asm volatile("global_load_dwordx4 %0, %1, off sc0 sc1" : "=v"(r) : "v"(p) : "memory");
  return r;
}
__device__ __forceinline__ void st16_cg(u16* p, u32 v){
  asm volatile("global_store_short %0, %1, off sc0 sc1" :: "v"(p), "v"(v) : "memory");
}
__device__ __forceinline__ void wait_vm0(){ asm volatile("s_waitcnt vmcnt(0)" ::: "memory"); }

__device__ __forceinline__ void bar_arrive(u32* bar){
  __hip_atomic_fetch_add(bar, 1u, __ATOMIC_RELAXED, __HIP_MEMORY_SCOPE_AGENT);
}
__device__ __forceinline__ void bar_spin(u32* bar, u32 tgt){
  while (__hip_atomic_load(bar, __ATOMIC_RELAXED, __HIP_MEMORY_SCOPE_AGENT) < tgt)
    __builtin_amdgcn_s_sleep(1);
}

// ---------------- dtype detection ----------------
__global__ __launch_bounds__(256) void k_detect(const u32* __restrict__ embw, u32* __restrict__ dflag){
  int tid = threadIdx.x;
  u32 cnt = 0;
  for (int t = 0; t < 32; ++t){
    u32 w = embw[t*256 + tid];
    u32 e = (w >> 7) & 0xFFu;
    cnt += (e >= 0xC0u) ? 1u : 0u;
  }
  atomicAdd(dflag, cnt);
}

// ---------------- pack (weights -> bf16/f32 in ws) ----------------

__global__ __launch_bounds__(256) void k_pack(
  const void* eWihF, const void* eWihB, const void* ebF, const void* ebB,
  const void* dWih, const void* dWhh, const void* db, const void* Wtag,
  const void* eWhhF, const void* eWhhB, const void* Watt, const void* btag,
  const u32* __restrict__ dflag,
  u16* __restrict__ WihCat, float* __restrict__ bcat, u16* __restrict__ WihH,
  u16* __restrict__ Wf, float* __restrict__ lbv, u16* __restrict__ WtagP,
  u16* __restrict__ WhhFb, u16* __restrict__ WhhBb, u16* __restrict__ Wattb,
  float* __restrict__ btagf)
{
  bool isf = (*dflag > 64u);
  long i = (long)blockIdx.x * 256 + threadIdx.x;
  if (i < 655360){                       // WihCat [2048][320] (K padded 300->320)
    long n = i / 320, e = i - n*320;
    WihCat[i] = (e < 300)
      ? f2bf(ldin(n < 1024 ? eWihF : eWihB, (size_t)(n & 1023)*300 + e, isf)) : (u16)0;
    return;
  }
  i -= 655360;
  if (i < 2048){ bcat[i] = ldin(i < 1024 ? ebF : ebB, (size_t)(i & 1023), isf); return; }
  i -= 2048;
  if (i < 1048576){                      // WihH [2048][512] = dec_Wih[:,512:1024]
    long n = i >> 9, k = i & 511;
    WihH[i] = f2bf(ldin(dWih, (size_t)n*1028 + 512 + k, isf));
    return;
  }
  i -= 1048576;
  if (i < 2097152){                      // Wf: gate weights in MFMA A-fragment layout
    long e  = i & 7;
    long ln = (i >> 3) & 63;
    long kt = (i >> 9) & 31;
    long rt = (i >> 14) & 3;
    long wgi = i >> 16;
    long n = rt*512 + wgi*16 + (ln & 15);
    long k = kt*32 + (ln >> 4)*8 + e;
    Wf[i] = f2bf((k < 512) ? ldin(dWih, (size_t)n*1028 + k, isf)
                           : ldin(dWhh, (size_t)n*512 + (k - 512), isf));
    return;
  }
  i -= 2097152;
  if (i < 8192){                         // lb [4][2048] = dec_b + onehot col
    long l = i >> 11, n = i & 2047;
    lbv[i] = ldin(db, n, isf) + ldin(dWih, (size_t)n*1028 + 1024 + l, isf);
    return;
  }
  i -= 8192;
  if (i < 8192){                         // WtagP [16][512] padded
    long n = i >> 9, k = i & 511;
    WtagP[i] = (n < 9) ? f2bf(ldin(Wtag, (size_t)n*512 + k, isf)) : (u16)0;
    return;
  }
  i -= 8192;
  if (i < 262144){ WhhFb[i] = f2bf(ldin(eWhhF, i, isf)); return; }
  i -= 262144;
  if (i < 262144){ WhhBb[i] = f2bf(ldin(eWhhB, i, isf)); return; }
  i -= 262144;
  if (i < 262144){ Wattb[i] = f2bf(ldin(Watt, i, isf)); return; }
  i -= 262144;
  if (i < 16){ btagf[i] = (i < 9) ? ldin(btag, i, isf) : 0.f; return; }
}

__global__ __launch_bounds__(256) void k_gather(
  const int* __restrict__ seqs, const void* __restrict__ emb,
  const u32* __restrict__ dflag, u16* __restrict__ X)
{
  bool isf = (*dflag > 64u);
  int idx = blockIdx.x * 256 + threadIdx.x;
  if (idx >= 8192*320) return;
  int row = idx / 320, e = idx - row*320;
  int s = row >> 5, b = row & 31;
  int tok = seqs[b*256 + s];
  X[idx] = (e < 300) ? f2bf(ldin(emb, (size_t)tok*300 + e, isf)) : (u16)0;
}

// ---------------- generic bf16 GEMM: C[M,N] = A[M,K] @ B[N,K]^T (+bias) ----------------

__global__ __launch_bounds__(256) void k_gemm(
  const u16* __restrict__ A, const u16* __restrict__ B, const float* __restrict__ bias,
  u16* __restrict__ C, int M, int N, int K)
{
  int mb = blockIdx.x * 32;
  int wave = threadIdx.x >> 6, lane = threadIdx.x & 63;
  int nb = blockIdx.y * 256 + wave * 64;
  int rlo = lane & 15, klane = (lane >> 4) * 8;
  f32x4 acc[2][4];
  #pragma unroll
  for (int i = 0; i < 2; ++i)
    #pragma unroll
    for (int j = 0; j < 4; ++j) acc[i][j] = (f32x4){0,0,0,0};
  for (int kk = 0; kk < K; kk += 32){
    bf16x8 a0 = *(const bf16x8*)(A + (size_t)(mb + rlo)*K + kk + klane);
    bf16x8 a1 = *(const bf16x8*)(A + (size_t)(mb + 16 + rlo)*K + kk + klane);
    #pragma unroll
    for (int nt = 0; nt < 4; ++nt){
      bf16x8 bv = *(const bf16x8*)(B + (size_t)(nb + nt*16 + rlo)*K + kk + klane);
      acc[0][nt] = mfma16(a0, bv, acc[0][nt]);
      acc[1][nt] = mfma16(a1, bv, acc[1][nt]);
    }
  }
  int rbase = (lane >> 4) * 4;
  #pragma unroll
  for (int mt = 0; mt < 2; ++mt)
    #pragma unroll
    for (int nt = 0; nt < 4; ++nt){
      int col = nb + nt*16 + rlo;
      float badd = bias ? bias[col] : 0.0f;
      #pragma unroll
      for (int r = 0; r < 4; ++r){
        int row = mb + mt*16 + rbase + r;
        C[(size_t)row*N + col] = f2bf(acc[mt][nt][r] + badd);
      }
    }
}

// ---------------- transpose h -> hT[b][d][j] ----------------

__global__ __launch_bounds__(256) void k_transp(const u16* __restrict__ hglob, u16* __restrict__ hT)
{
  __shared__ u16 tile_t[64][264];
  int b = blockIdx.x >> 3, d0 = (blockIdx.x & 7) * 64;
  int t = threadIdx.x;
  for (int rr = 0; rr < 16; ++rr){
    int c = rr*256 + t;
    int j = c >> 4, dq = (c & 15) * 4;
    ushort4 ld = *(const ushort4*)(hglob + ((size_t)(j*32 + b)*512 + d0 + dq));
    tile_t[dq + 0][j] = ld.x;
    tile_t[dq + 1][j] = ld.y;
    tile_t[dq + 2][j] = ld.z;
    tile_t[dq + 3][j] = ld.w;
  }
  __syncthreads();
  for (int rr = 0; rr < 8; ++rr){
    int c = rr*256 + t;
    int d = c >> 5, jq = (c & 31) * 8;
    *(uint4*)(hT + ((size_t)(b*512 + d0 + d)*256 + jq)) = *(const uint4*)&tile_t[d][jq];
  }
}

// ---------------- encoder: persistent, 32 WGs (16 per direction), relaxed sync ----------------

__global__ __launch_bounds__(256, 1) void k_encoder(
  const u16* __restrict__ XW, const u16* __restrict__ WhhF, const u16* __restrict__ WhhB,
  u16* __restrict__ hglob, u16* __restrict__ hstate, u32* ctrl)
{
  int wg = blockIdx.x;
  int d = wg >> 4, w = wg & 15;
  const u16* Whh = d ? WhhB : WhhF;
  u32* bar = ctrl + d * 64;
  int tid = threadIdx.x, wave = tid >> 6, lane = tid & 63;
  int cc = lane & 15, q = lane >> 4, klane = q * 8, rbase = q * 4;
  __shared__ __align__(16) u16 hblk[8192];     // [b][256] swizzled
  __shared__ float g_lds[4][32][16];
  __shared__ float c_sh[512];
  c_sh[tid] = 0.f; c_sh[tid + 256] = 0.f;
  __syncthreads();

  for (int t = 0; t < 256; ++t){
    int srow = d ? (255 - t) : t;
    const u16* hr = hstate + (size_t)(d*2 + (t & 1)) * 8192;
    u16*       hw = hstate + (size_t)(d*2 + ((t & 1) ^ 1)) * 8192;

    // stage h block (32 x 256) from MALL into LDS
    {
      int c0 = tid, c1 = tid + 256, c2 = tid + 512, c3 = tid + 768;
      uint4 v0 = ldx4_cg(hr + (c0 >> 5)*256 + (c0 & 31)*8);
      uint4 v1 = ldx4_cg(hr + (c1 >> 5)*256 + (c1 & 31)*8);
      uint4 v2 = ldx4_cg(hr + (c2 >> 5)*256 + (c2 & 31)*8);
      uint4 v3 = ldx4_cg(hr + (c3 >> 5)*256 + (c3 & 31)*8);
      wait_vm0();
      *(uint4*)(hblk + (c0 >> 5)*256 + (((c0 & 31) ^ ((c0 >> 5) & 7)))*8) = v0;
      *(uint4*)(hblk + (c1 >> 5)*256 + (((c1 & 31) ^ ((c1 >> 5) & 7)))*8) = v1;
      *(uint4*)(hblk + (c2 >> 5)*256 + (((c2 & 31) ^ ((c2 >> 5) & 7)))*8) = v2;
      *(uint4*)(hblk + (c3 >> 5)*256 + (((c3 & 31) ^ ((c3 >> 5) & 7)))*8) = v3;
    }
    __syncthreads();

    // h @ Whh^T for this WG's 16 cols x 4 gates
    {
      int ncol = wave*256 + w*16 + cc;
      const u16* Brow = Whh + (size_t)ncol*256;
      f32x4 acc0 = {0,0,0,0}, acc1 = {0,0,0,0};
      #pragma unroll
      for (int kt = 0; kt < 8; ++kt){
        bf16x8 bv = *(const bf16x8*)(Brow + kt*32 + klane);
        bf16x8 a0 = *(const bf16x8*)(hblk + cc*256 + ((kt*4 + q) ^ (cc & 7))*8);
        bf16x8 a1 = *(const bf16x8*)(hblk + (cc + 16)*256 + ((kt*4 + q) ^ (cc & 7))*8);
        acc0 = mfma16(a0, bv, acc0);
        acc1 = mfma16(a1, bv, acc1);
      }
      #pragma unroll
      for (int r = 0; r < 4; ++r){
        g_lds[wave][rbase + r][cc]      = acc0[r];
        g_lds[wave][16 + rbase + r][cc] = acc1[r];
      }
    }
    __syncthreads();

    // pointwise
    for (int e = tid; e < 512; e += 256){
      int b_ = e >> 4, jc = e & 15;
      int j = w*16 + jc;
      float pre[4];
      #pragma unroll
      for (int g2 = 0; g2 < 4; ++g2)
        pre[g2] = g_lds[g2][b_][jc] + bf2f(XW[(size_t)(srow*32 + b_)*2048 + d*1024 + g2*256 + j]);
      float iv = sigm(pre[0]), fv = sigm(pre[1]);
      float gv = tanhf(pre[2]), ov = sigm(pre[3]);
      float cv = fv * c_sh[e] + iv * gv;
      c_sh[e] = cv;
      u16 hb = f2bf(ov * tanhf(cv));
      st16_cg(hw + b_*256 + j, (u32)hb);
      __builtin_nontemporal_store(hb, hglob + (size_t)(srow*32 + b_)*512 + d*256 + j);
    }
    wait_vm0();
    __syncthreads();
    if (tid == 0){
      bar_arrive(bar);
      bar_spin(bar, (u32)(t + 1) * 16u);
    }
    __syncthreads();
  }
}

// ---------------- decoder: persistent, 32 WGs x 512 threads, relaxed sync ----------------
// WG b: full attention for batch b (Wh pinned in VGPRs, hT L2-cached)
//       + gate-output dims [b*16, b*16+16) x 4 gates for ALL batches (Wf L2-cached).
// Cross-WG exchange (s, ctx) via MALL (sc0 sc1) + relaxed flags; staged into LDS.

__global__ __launch_bounds__(512, 1) void k_decoder(
  const u16* __restrict__ Whb, const u16* __restrict__ hT,
  const u16* __restrict__ Wf, const u16* __restrict__ Xh, const float* __restrict__ lbv,
  u16* __restrict__ Ain,          // [2][32][1024] bf16: [b][0:512)=ctx, [512:1024)=s
  u16* __restrict__ aouts,        // [32768][512] bf16
  u32* bar1, u32* bar2)
{
  extern __shared__ __align__(16) u16 ablk[];   // [32][1024], 16B-chunk XOR-swizzled (64KB)
  __shared__ float score_lds[256];
  __shared__ __align__(16) u16 att_bf[256];
  __shared__ float gbuf[4][16][33];
  __shared__ float c_lds[512];
  const int wg = blockIdx.x, tid = threadIdx.x;
  const int wave = tid >> 6, lane = tid & 63;
  const int q = lane >> 4, cc = lane & 15;
  c_lds[tid] = 0.0f;

  // pin Wh_b A-fragments in VGPRs: wave holds score rows [wave*32, wave*32+32)
  bf16x8 wh[2][16];
  #pragma unroll
  for (int rt = 0; rt < 2; ++rt)
    #pragma unroll
    for (int kt = 0; kt < 16; ++kt){
      int row = wave*32 + rt*16 + cc;
      wh[rt][kt] = *(const bf16x8*)(Whb + ((size_t)(row*32 + wg))*512 + kt*32 + q*8);
    }
  const int grt = wave >> 1, gct = wave & 1;    // gate tile (gate, batch-half) per wave
  const int bcol = gct*16 + cc;
  const u16* WfW = Wf + (size_t)wg*65536;
  __syncthreads();

  for (int iter = 0; iter < 1024; ++iter){
    const int l = iter >> 8, t = iter & 255;
    u16* AinC = Ain + (iter & 1)*32768;
    u16* AinN = Ain + ((iter & 1) ^ 1)*32768;

    // stage s-block (32 x 512) from MALL -> ablk chunks [64,128)
    {
      int c0 = tid, c1 = tid + 512, c2 = tid + 1024, c3 = tid + 1536;
      uint4 v0 = ldx4_cg(AinC + (c0 >> 6)*1024 + 512 + (c0 & 63)*8);
      uint4 v1 = ldx4_cg(AinC + (c1 >> 6)*1024 + 512 + (c1 & 63)*8);
      uint4 v2 = ldx4_cg(AinC + (c2 >> 6)*1024 + 512 + (c2 & 63)*8);
      uint4 v3 = ldx4_cg(AinC + (c3 >> 6)*1024 + 512 + (c3 & 63)*8);
      wait_vm0();
      *(uint4*)(ablk + (c0 >> 6)*1024 + (64 + ((c0 & 63) ^ ((c0 >> 6) & 7)))*8) = v0;
      *(uint4*)(ablk + (c1 >> 6)*1024 + (64 + ((c1 & 63) ^ ((c1 >> 6) & 7)))*8) = v1;
      *(uint4*)(ablk + (c2 >> 6)*1024 + (64 + ((c2 & 63) ^ ((c2 >> 6) & 7)))*8) = v2;
      *(uint4*)(ablk + (c3 >> 6)*1024 + (64 + ((c3 & 63) ^ ((c3 >> 6) & 7)))*8) = v3;
    }
    __syncthreads();

    // scores: MFMA(Wh-VGPR, own-s broadcast)
    f32x4 sa0 = {0,0,0,0}, sa1 = {0,0,0,0};
    #pragma unroll
    for (int kt = 0; kt < 16; ++kt){
      bf16x8 sv = *(const bf16x8*)(ablk + wg*1024 + ((64 + kt*4 + q) ^ (wg & 7))*8);
      sa0 = mfma16(wh[0][kt], sv, sa0);
      sa1 = mfma16(wh[1][kt], sv, sa1);
    }
    if (cc == 0){
      #pragma unroll
      for (int r = 0; r < 4; ++r){
        score_lds[wave*32      + q*4 + r] = sa0[r];
        score_lds[wave*32 + 16 + q*4 + r] = sa1[r];
      }
    }
    __syncthreads();

    // softmax (wave 0, 4 scores/lane)
    if (wave == 0){
      float x0 = score_lds[lane*4+0], x1 = score_lds[lane*4+1];
      float x2 = score_lds[lane*4+2], x3 = score_lds[lane*4+3];
      float m = fmaxf(fmaxf(x0,x1), fmaxf(x2,x3));
      #pragma unroll
      for (int off = 32; off >= 1; off >>= 1) m = fmaxf(m, __shfl_xor(m, off));
      float e0 = __expf(x0-m), e1 = __expf(x1-m), e2 = __expf(x2-m), e3 = __expf(x3-m);
      float s = e0+e1+e2+e3;
      #pragma unroll
      for (int off = 32; off >= 1; off >>= 1) s += __shfl_xor(s, off);
      float inv = 1.0f / s;
      att_bf[lane*4+0] = f2bf(e0*inv);
      att_bf[lane*4+1] = f2bf(e1*inv);
      att_bf[lane*4+2] = f2bf(e2*inv);
      att_bf[lane*4+3] = f2bf(e3*inv);
    }
    __syncthreads();

    // ctx: MFMA(att row-0, hT B-frags). wave owns dims [wave*64, wave*64+64)
    f32x4 ca0 = {0,0,0,0}, ca1 = {0,0,0,0}, ca2 = {0,0,0,0}, ca3 = {0,0,0,0};
    #pragma unroll
    for (int jt = 0; jt < 8; ++jt){
      uint4 au = {0,0,0,0};
      if (cc == 0) au = *(const uint4*)(att_bf + jt*32 + q*8);
      bf16x8 af = *(bf16x8*)&au;
      const u16* hb = hT + ((size_t)(wg*512 + wave*64 + cc))*256 + jt*32 + q*8;
      ca0 = mfma16(af, *(const bf16x8*)(hb +  0*256), ca0);
      ca1 = mfma16(af, *(const bf16x8*)(hb + 16*256), ca1);
      ca2 = mfma16(af, *(const bf16x8*)(hb + 32*256), ca2);
      ca3 = mfma16(af, *(const bf16x8*)(hb + 48*256), ca3);
    }
    if (q == 0){
      u16* dst = AinC + wg*1024 + wave*64 + cc;
      st16_cg(dst +  0, (u32)f2bf(ca0[0]));
      st16_cg(dst + 16, (u32)f2bf(ca1[0]));
      st16_cg(dst + 32, (u32)f2bf(ca2[0]));
      st16_cg(dst + 48, (u32)f2bf(ca3[0]));
    }
    wait_vm0();
    __syncthreads();                     // all ctx stores of this WG acked at MALL
    if (tid == 0) bar_arrive(bar2);

    // gate s-half (K 512..1023) — overlaps other WGs' ctx production
    f32x4 ga = {0,0,0,0};
    #pragma unroll
    for (int kt = 16; kt < 32; ++kt){
      bf16x8 wa = *(const bf16x8*)(WfW + ((grt*32 + kt)*64 + lane)*8);
      bf16x8 av = *(const bf16x8*)(ablk + bcol*1024 + ((kt*4 + q) ^ (bcol & 7))*8);
      ga = mfma16(wa, av, ga);
    }
    if (tid == 0) bar_spin(bar2, 32u*(u32)(iter+1));
    __syncthreads();

    // stage ctx-block (32 x 512) from MALL -> ablk chunks [0,64)
    {
      int c0 = tid, c1 = tid + 512, c2 = tid + 1024, c3 = tid + 1536;
      uint4 v0 = ldx4_cg(AinC + (c0 >> 6)*1024 + (c0 & 63)*8);
      uint4 v1 = ldx4_cg(AinC + (c1 >> 6)*1024 + (c1 & 63)*8);
      uint4 v2 = ldx4_cg(AinC + (c2 >> 6)*1024 + (c2 & 63)*8);
      uint4 v3 = ldx4_cg(AinC + (c3 >> 6)*1024 + (c3 & 63)*8);
      wait_vm0();
      *(uint4*)(ablk + (c0 >> 6)*1024 + (((c0 & 63) ^ ((c0 >> 6) & 7)))*8) = v0;
      *(uint4*)(ablk + (c1 >> 6)*1024 + (((c1 & 63) ^ ((c1 >> 6) & 7)))*8) = v1;
      *(uint4*)(ablk + (c2 >> 6)*1024 + (((c2 & 63) ^ ((c2 >> 6) & 7)))*8) = v2;
      *(uint4*)(ablk + (c3 >> 6)*1024 + (((c3 & 63) ^ ((c3 >> 6) & 7)))*8) = v3;
    }
    __syncthreads();

    // gate ctx-half (K 0..511)
    #pragma unroll
    for (int kt = 0; kt < 16; ++kt){
      bf16x8 wa = *(const bf16x8*)(WfW + ((grt*32 + kt)*64 + lane)*8);
      bf16x8 av = *(const bf16x8*)(ablk + bcol*1024 + ((kt*4 + q) ^ (bcol & 7))*8);
      ga = mfma16(wa, av, ga);
    }
    #pragma unroll
    for (int r = 0; r < 4; ++r) gbuf[grt][q*4 + r][bcol] = ga[r];
    __syncthreads();

    // pointwise: thread = (b_, dd); this WG owns h-dims [wg*16, wg*16+16)
    {
      const int b_ = tid >> 4, dd = tid & 15;
      const int gj = wg*16 + dd;
      float pre[4];
      #pragma unroll
      for (int g = 0; g < 4; ++g){
        int n = g*512 + gj;
        pre[g] = gbuf[g][dd][b_] + bf2f(Xh[(size_t)(t*32 + b_)*2048 + n]) + lbv[l*2048 + n];
      }
      float iv = sigm(pre[0]), fv = sigm(pre[1]);
      float gv = tanhf(pre[2]), ov = sigm(pre[3]);
      float cv = fv * c_lds[tid] + iv * gv;
      c_lds[tid] = cv;
      u16 hb = f2bf(ov * tanhf(cv));
      st16_cg(AinN + b_*1024 + 512 + gj, (u32)hb);
      __builtin_nontemporal_store(hb, aouts + (size_t)((l*256 + t)*32 + b_)*512 + gj);
    }
    wait_vm0();
    __syncthreads();
    if (tid == 0){
      bar_arrive(bar1);
      bar_spin(bar1, 32u*(u32)(iter+1));
    }
    __syncthreads();
  }
}

// ---------------- tag projection ----------------

__global__ __launch_bounds__(256) void k_tag(
  const u16* __restrict__ aouts, const u16* __restrict__ WtagP, const float* __restrict__ btagf,
  const u32* __restrict__ dflag, void* __restrict__ out)
{
  bool isf = (*dflag > 64u);
  int wave = threadIdx.x >> 6, lane = threadIdx.x & 63;
  int mb = (blockIdx.x * 4 + wave) * 16;
  int cc = lane & 15, klane = (lane >> 4) * 8;
  f32x4 acc = {0,0,0,0};
  const u16* Arow = aouts + (size_t)(mb + cc)*512;
  const u16* Brow = WtagP + cc*512;
  #pragma unroll
  for (int kk = 0; kk < 512; kk += 32){
    bf16x8 av = *(const bf16x8*)(Arow + kk + klane);
    bf16x8 bv = *(const bf16x8*)(Brow + kk + klane);
    acc = mfma16(av, bv, acc);
  }
  int rbase = (lane >> 4) * 4;
  if (cc < 9){
    float bt = btagf[cc];
    #pragma unroll
    for (int r = 0; r < 4; ++r){
      int row = mb + rbase + r;
      float v = acc[r] + bt;
      if (isf) ((float*)out)[(size_t)row*9 + cc] = v;
      else     ((u16*)out)[(size_t)row*9 + cc] = f2bf(v);
    }
  }
}

// ---------------- host ----------------

extern "C" void kernel_launch(void* const* d_in, const int* in_sizes, int n_in,
                              void* d_out, int out_size, void* d_ws, size_t ws_size,
                              hipStream_t stream)
{
  (void)in_sizes; (void)n_in; (void)out_size;
  if (ws_size < 98625536ull) return;

  const int* seqs = (const int*)d_in[0];

  char* ws = (char*)d_ws;
  u32*    ctrl   = (u32*)(ws + 0);          // barEncF@0 barEncB@64 barDec1@128 barDec2@160 dflag@240
  u32*    dflag  = ctrl + 240;
  u16*    Ain    = (u16*)(ws + 1024);       // [2][32][1024] bf16
  u16*    hstate = (u16*)(ws + 132096);     // [4][32][256]
  // memset end = 197632 (round up to 263168)
  u16*    WihCat = (u16*)(ws + 263168);     // [2048][320]
  float*  bcat   = (float*)(ws + 1573888);  // [2048]
  u16*    WihH   = (u16*)(ws + 1582080);    // [2048][512]
  u16*    Wf     = (u16*)(ws + 3679232);    // [32][4][32][64][8] fragment layout (4MB)
  float*  lbv    = (float*)(ws + 7873536);  // [4][2048]
  u16*    WtagP  = (u16*)(ws + 7906304);    // [16][512]
  u16*    WhhFb  = (u16*)(ws + 7922688);    // [1024][256]
  u16*    WhhBb  = (u16*)(ws + 8446976);    // [1024][256]
  u16*    Wattb  = (u16*)(ws + 8971264);    // [512][512]
  float*  btagf  = (float*)(ws + 9495552);  // [16]
  u16*    X      = (u16*)(ws + 9496576);    // [8192][320]
  u16*    XWXh   = (u16*)(ws + 14739456);   // [8192][2048] XW, later Xh (aliased)
  u16*    aouts  = (u16*)(ws + 48293888);   // [32768][512]; first 8.4MB doubles as hglob pre-decoder
  u16*    hglob  = (u16*)(ws + 48293888);   // alias (dead before decoder writes aouts)
  u16*    hT     = (u16*)(ws + 81848320);   // [32][512][256]
  u16*    Whb    = (u16*)(ws + 90236928);   // [8192][512]

  hipMemsetAsync(d_ws, 0, 263168, stream);

  k_detect<<<1, 256, 0, stream>>>((const u32*)d_in[1], dflag);
  k_pack<<<17993, 256, 0, stream>>>(
      d_in[2], d_in[5], d_in[4], d_in[7], d_in[9], d_in[10], d_in[11], d_in[12],
      d_in[3], d_in[6], d_in[8], d_in[13], dflag,
      WihCat, bcat, WihH, Wf, lbv, WtagP, WhhFb, WhhBb, Wattb, btagf);
  k_gather<<<10240, 256, 0, stream>>>(seqs, d_in[1], dflag, X);
  // XW = X @ [Wih_f; Wih_b]^T + bias
  k_gemm<<<dim3(256, 8), 256, 0, stream>>>(X, WihCat, bcat, XWXh, 8192, 2048, 320);
  k_encoder<<<32, 256, 0, stream>>>(XWXh, WhhFb, WhhBb, hglob, hstate, ctrl);
  // Wh = h @ W_att^T ; Xh = h @ Wih_h^T (Xh aliases XW)
  k_gemm<<<dim3(256, 2), 256, 0, stream>>>(hglob, Wattb, nullptr, Whb, 8192, 512, 512);
  k_gemm<<<dim3(256, 8), 256, 0, stream>>>(hglob, WihH, nullptr, XWXh, 8192, 2048, 512);
  k_transp<<<256, 256, 0, stream>>>(hglob, hT);

  k_decoder<<<32, 512, 65536, stream>>>(Whb, hT, Wf, XWXh, lbv, Ain, aouts,
                                        ctrl + 128, ctrl + 160);
  k_tag<<<512, 256, 0, stream>>>(aouts, WtagP, btagf, dflag, d_out);
}